// Round 10
// baseline (575.846 us; speedup 1.0000x reference)
//
#include <hip/hip_runtime.h>
#include <hip/hip_bf16.h>

// Shapes (fixed by the problem)
#define VV 50000
#define EE 128
#define HH 128
#define OO 128
#define BB 64
#define TT 512

typedef __bf16 bf16_t;
typedef __attribute__((ext_vector_type(8))) __bf16 bf16x8;
typedef __attribute__((ext_vector_type(4))) __bf16 bf16x4;
typedef __attribute__((ext_vector_type(4))) float floatx4;

__device__ __forceinline__ bf16x8 ldb8(const bf16_t* p) {
    return *reinterpret_cast<const bf16x8*>(p);
}

// load 8 consecutive fp32, round to bf16 fragment (two float4 loads)
__device__ __forceinline__ bf16x8 ldf8_bf(const float* p) {
    const float4* q = reinterpret_cast<const float4*>(p);
    float4 u = q[0], v = q[1];
    bf16x8 r;
    r[0] = (__bf16)u.x; r[1] = (__bf16)u.y; r[2] = (__bf16)u.z; r[3] = (__bf16)u.w;
    r[4] = (__bf16)v.x; r[5] = (__bf16)v.y; r[6] = (__bf16)v.z; r[7] = (__bf16)v.w;
    return r;
}

__device__ __forceinline__ float fast_rcp(float x) { return __builtin_amdgcn_rcpf(x); }
__device__ __forceinline__ float sigmoid_f(float x) {
    return fast_rcp(1.0f + __expf(-x));
}
__device__ __forceinline__ float tanh_f(float x) {
    float e = __expf(2.0f * x);
    return 1.0f - 2.0f * fast_rcp(e + 1.0f);
}

// LDS-only barrier: wait LDS ops, sync — do NOT drain vmcnt (hist stores and
// gx ring-prefetch loads stay in flight across steps).
__device__ __forceinline__ void lds_barrier() {
    asm volatile("s_waitcnt lgkmcnt(0)\n\ts_barrier" ::: "memory");
}

// -------- K0: preconvert small weights fp32->bf16 + fold gx bias.
// (emb is NOT converted — k12 converts inline; saves a 38 MB pass)
__global__ __launch_bounds__(256) void k0_conv(
    const float* __restrict__ we,
    const float* __restrict__ wihf, const float* __restrict__ wihb,
    const float* __restrict__ whhf, const float* __restrict__ whhb,
    const float* __restrict__ wh2o,
    const float* __restrict__ bihf, const float* __restrict__ bhhf,
    const float* __restrict__ bihb, const float* __restrict__ bhhb,
    bf16_t* __restrict__ we_bf,
    bf16_t* __restrict__ wih_bf, bf16_t* __restrict__ whh_bf,
    bf16_t* __restrict__ wh2o_bf, float* __restrict__ gxbias) {
    int tid = blockIdx.x * 256 + threadIdx.x;
    int np = gridDim.x * 256;
    for (int i = tid; i < HH * EE; i += np) we_bf[i] = (bf16_t)we[i];
    for (int i = tid; i < 384 * HH; i += np) {
        wih_bf[i] = (bf16_t)wihf[i];
        wih_bf[384 * HH + i] = (bf16_t)wihb[i];
        whh_bf[i] = (bf16_t)whhf[i];
        whh_bf[384 * HH + i] = (bf16_t)whhb[i];
    }
    for (int i = tid; i < OO * 256; i += np) wh2o_bf[i] = (bf16_t)wh2o[i];
    if (tid < 768) {
        int dir = tid / 384, n = tid % 384;
        const float* bih = dir ? bihb : bihf;
        const float* bhh = dir ? bhhb : bhhf;
        gxbias[tid] = bih[n] + (n < 256 ? bhh[n] : 0.0f);  // bhh_n goes in K3's C-init
    }
}

// -------- K12 (fused K1+K2), 4 timesteps per block: xh tiles in LDS, then
// gx3[(dir*16+g4)][t][n][4] = xh @ Wih^T + gxbias for both dirs.
// 4-t batching amortizes the Wih reads (was re-read per t) 4x.
__global__ __launch_bounds__(256) void k12_gx(const int* __restrict__ X,
                                              const float* __restrict__ emb,
                                              const bf16_t* __restrict__ we_bf,
                                              const float* __restrict__ be,
                                              const bf16_t* __restrict__ wih_bf,
                                              const float* __restrict__ gxbias,
                                              bf16_t* __restrict__ gx3) {
    int blk = blockIdx.x;            // 0..511 = tq*4 + g
    int tq = blk >> 2;
    int g = blk & 3;                 // 16-sample tile
    int lane = threadIdx.x & 63;
    int w2 = threadIdx.x >> 6;       // wave 0..3
    int quad = lane >> 4, col = lane & 15;

    __shared__ bf16_t xs[4][16 * 136];   // 4 xh tiles, row-padded

    // stage 1 x4: xh = emb[X] @ We^T + be (A rows = 16 samples at t=4tq+tt)
#pragma unroll
    for (int tt = 0; tt < 4; ++tt) {
        int t = 4 * tq + tt;
        int v = X[(g * 16 + col) * TT + t];
        bf16x8 a[4];
#pragma unroll
        for (int kc = 0; kc < 4; ++kc)
            a[kc] = ldf8_bf(emb + (size_t)v * EE + kc * 32 + quad * 8);
#pragma unroll
        for (int tl = 0; tl < 2; ++tl) {
            int n = 32 * w2 + 16 * tl + col;
            floatx4 acc = {0.f, 0.f, 0.f, 0.f};
#pragma unroll
            for (int kc = 0; kc < 4; ++kc) {
                bf16x8 bw = ldb8(we_bf + (size_t)n * EE + kc * 32 + quad * 8);
                acc = __builtin_amdgcn_mfma_f32_16x16x32_bf16(a[kc], bw, acc, 0, 0, 0);
            }
            float bias = be[n];
#pragma unroll
            for (int r = 0; r < 4; ++r)
                xs[tt][(quad * 4 + r) * 136 + n] = (bf16_t)(acc[r] + bias);
        }
    }
    __syncthreads();

    // stage 2: gx = xh @ Wih^T + gxbias, both dirs; Wih loaded once per n-tile
    bf16x8 a2[4][4];
#pragma unroll
    for (int tt = 0; tt < 4; ++tt)
#pragma unroll
        for (int kc = 0; kc < 4; ++kc)
            a2[tt][kc] = ldb8(xs[tt] + col * 136 + kc * 32 + quad * 8);

#pragma unroll
    for (int tl = 0; tl < 12; ++tl) {
        int idx = w2 * 12 + tl;          // 0..47
        int dir = idx >= 24;
        int n = (idx - dir * 24) * 16 + col;   // 0..383
        bf16x8 bw[4];
#pragma unroll
        for (int kc = 0; kc < 4; ++kc)
            bw[kc] = ldb8(wih_bf + ((size_t)dir * 384 + n) * HH + kc * 32 + quad * 8);
        float bias = gxbias[dir * 384 + n];
#pragma unroll
        for (int tt = 0; tt < 4; ++tt) {
            int t = 4 * tq + tt;
            floatx4 acc = {0.f, 0.f, 0.f, 0.f};
#pragma unroll
            for (int kc = 0; kc < 4; ++kc)
                acc = __builtin_amdgcn_mfma_f32_16x16x32_bf16(a2[tt][kc], bw[kc], acc, 0, 0, 0);
            bf16x4 pack;
#pragma unroll
            for (int r = 0; r < 4; ++r)
                pack[r] = (__bf16)(acc[r] + bias);   // D row r -> sample 16g+quad*4+r
            *reinterpret_cast<bf16x4*>(
                gx3 + (((size_t)(dir * 16 + 4 * g + quad) * TT + t) * 384 + n) * 4) = pack;
        }
    }
}

// -------- K3: masked GRU recurrence, BOTH directions fused in one block.
// grid (16 groups of 4 samples) = 16 blocks, 512 threads = 8 waves.
// The two recurrences are independent: interleaving them doubles the ILP
// exactly where the single-dir version stalled (ds_read latency, MFMA chain,
// transcendental chain), while paying ONE barrier + one serial chain per step.
// Broadcast A-layout + register select per R9 (D rows repeat with period 4).
#define HPAD 144
#define HBUF (4 * HPAD)
__global__ __launch_bounds__(512) void k3_gru(const bf16_t* __restrict__ gx3,
                                              const bf16_t* __restrict__ whh_bf,
                                              const float* __restrict__ bhh_f,
                                              const float* __restrict__ bhh_b,
                                              const int* __restrict__ lens,
                                              bf16_t* __restrict__ hist2) {
    int g16 = blockIdx.x;    // 4-sample group: samples 4*g16 .. 4*g16+3

    int tid = threadIdx.x;
    int w = tid >> 6;        // wave 0..7
    int lane = tid & 63;
    int quad = lane >> 4, col = lane & 15;
    int j = 16 * w + col;    // owned hidden column

    // [dir][buf][4 rows * HPAD]
    __shared__ bf16_t hl[2][2][HBUF];
    for (int i = tid; i < 2 * 2 * HBUF; i += 512) (&hl[0][0][0])[i] = (bf16_t)0.f;

    int len1 = lens[4 * g16 + quad];      // this lane's sample
    int Lmax = max(max(lens[4 * g16], lens[4 * g16 + 1]),
                   max(lens[4 * g16 + 2], lens[4 * g16 + 3]));

    float bhnF = bhh_f[256 + j];
    float bhnB = bhh_b[256 + j];

    // Whh B-fragments for both dirs, resident (2*48 VGPRs)
    bf16x8 Bw[2][3][4];
#pragma unroll
    for (int dir = 0; dir < 2; ++dir)
#pragma unroll
        for (int gate = 0; gate < 3; ++gate)
#pragma unroll
            for (int kc = 0; kc < 4; ++kc)
                Bw[dir][gate][kc] = ldb8(whh_bf + ((size_t)dir * 384 + gate * 128 + j) * HH + kc * 32 + quad * 8);

    const bf16_t* gbF = gx3 + (size_t)(0 * 16 + g16) * TT * 1536;
    const bf16_t* gbB = gx3 + (size_t)(1 * 16 + g16) * TT * 1536;
    bf16_t* hbF = hist2 + (size_t)(0 * 16 + g16) * TT * 512;
    bf16_t* hbB = hist2 + (size_t)(1 * 16 + g16) * TT * 512;
    int loff[3];
#pragma unroll
    for (int gate = 0; gate < 3; ++gate)
        loff[gate] = (gate * 128 + j) * 4 + quad;
    int hoff = quad * 128 + j;
    int aoff = (col & 3) * HPAD + quad * 8;   // broadcast A-read offset

    float hF = 0.f, hB = 0.f;
    int S4 = (Lmax + 3) & ~3;
    bool lowquad = (quad & 1) == 0;
    bool lowhalf = (quad & 2) == 0;

    // prefetch ring, depth 4, both dirs (raw bf16; convert at consumption)
    __bf16 ring[4][3][2];
#pragma unroll
    for (int u = 0; u < 4; ++u) {
        int tF = min(u, Lmax - 1);
        int tB = min(max(Lmax - 1 - u, 0), Lmax - 1);
#pragma unroll
        for (int gate = 0; gate < 3; ++gate) {
            ring[u][gate][0] = gbF[(size_t)tF * 1536 + loff[gate]];
            ring[u][gate][1] = gbB[(size_t)tB * 1536 + loff[gate]];
        }
    }
    lds_barrier();   // zero-init visible

    for (int sb = 0; sb < S4; sb += 4) {
#pragma unroll
        for (int u = 0; u < 4; ++u) {
            int s = sb + u;
            int tF = min(s, Lmax - 1);                       // clamped tail
            int tB = min(max(Lmax - 1 - s, 0), Lmax - 1);
            const bf16_t* hcF = hl[0][s & 1];
            const bf16_t* hcB = hl[1][s & 1];
            bf16_t* hnF = hl[0][(s + 1) & 1];
            bf16_t* hnB = hl[1][(s + 1) & 1];

            // consume ring slot u (loads issued 4 steps ago)
            float gxF0 = (float)ring[u][0][0], gxB0 = (float)ring[u][0][1];
            float gxF1 = (float)ring[u][1][0], gxB1 = (float)ring[u][1][1];
            float gxF2 = (float)ring[u][2][0], gxB2 = (float)ring[u][2][1];

            // A fragments, both dirs (broadcast rows: sample = row & 3)
            bf16x8 aF[4], aB[4];
#pragma unroll
            for (int kc = 0; kc < 4; ++kc) {
                aF[kc] = ldb8(hcF + aoff + kc * 32);
                aB[kc] = ldb8(hcB + aoff + kc * 32);
            }

            // 6 independent MFMA chains (3 gates x 2 dirs)
            floatx4 crF = {0.f, 0.f, 0.f, 0.f}, crB = {0.f, 0.f, 0.f, 0.f};
            floatx4 czF = {0.f, 0.f, 0.f, 0.f}, czB = {0.f, 0.f, 0.f, 0.f};
            floatx4 cnF = {bhnF, bhnF, bhnF, bhnF}, cnB = {bhnB, bhnB, bhnB, bhnB};
#pragma unroll
            for (int kc = 0; kc < 4; ++kc) {
                crF = __builtin_amdgcn_mfma_f32_16x16x32_bf16(aF[kc], Bw[0][0][kc], crF, 0, 0, 0);
                crB = __builtin_amdgcn_mfma_f32_16x16x32_bf16(aB[kc], Bw[1][0][kc], crB, 0, 0, 0);
                czF = __builtin_amdgcn_mfma_f32_16x16x32_bf16(aF[kc], Bw[0][1][kc], czF, 0, 0, 0);
                czB = __builtin_amdgcn_mfma_f32_16x16x32_bf16(aB[kc], Bw[1][1][kc], czB, 0, 0, 0);
                cnF = __builtin_amdgcn_mfma_f32_16x16x32_bf16(aF[kc], Bw[0][2][kc], cnF, 0, 0, 0);
                cnB = __builtin_amdgcn_mfma_f32_16x16x32_bf16(aB[kc], Bw[1][2][kc], cnB, 0, 0, 0);
            }

            // refill ring slot u for step s+4, both dirs
            {
                int sn = s + 4;
                int tFn = min(sn, Lmax - 1);
                int tBn = min(max(Lmax - 1 - sn, 0), Lmax - 1);
#pragma unroll
                for (int gate = 0; gate < 3; ++gate) {
                    ring[u][gate][0] = gbF[(size_t)tFn * 1536 + loff[gate]];
                    ring[u][gate][1] = gbB[(size_t)tBn * 1536 + loff[gate]];
                }
            }

            // register select: reg r = gates of sample r; this lane's sample = quad
            float aRF = lowhalf ? (lowquad ? crF[0] : crF[1]) : (lowquad ? crF[2] : crF[3]);
            float aZF = lowhalf ? (lowquad ? czF[0] : czF[1]) : (lowquad ? czF[2] : czF[3]);
            float aNF = lowhalf ? (lowquad ? cnF[0] : cnF[1]) : (lowquad ? cnF[2] : cnF[3]);
            float aRB = lowhalf ? (lowquad ? crB[0] : crB[1]) : (lowquad ? crB[2] : crB[3]);
            float aZB = lowhalf ? (lowquad ? czB[0] : czB[1]) : (lowquad ? czB[2] : czB[3]);
            float aNB = lowhalf ? (lowquad ? cnB[0] : cnB[1]) : (lowquad ? cnB[2] : cnB[3]);

            // gate math, both dirs (independent chains -> ILP)
            bool live = (s < Lmax);
            bool updF = live && (tF < len1);
            bool updB = live && (tB < len1);
            {
                float rg = sigmoid_f(aRF + gxF0);
                float zg = sigmoid_f(aZF + gxF1);
                float ng = tanh_f(gxF2 + rg * aNF);
                float hnew = ng + zg * (hF - ng);
                hF = updF ? hnew : hF;
            }
            {
                float rg = sigmoid_f(aRB + gxB0);
                float zg = sigmoid_f(aZB + gxB1);
                float ng = tanh_f(gxB2 + rg * aNB);
                float hnew = ng + zg * (hB - ng);
                hB = updB ? hnew : hB;
            }
            bf16_t hF16 = (bf16_t)hF, hB16 = (bf16_t)hB;
            hnF[quad * HPAD + j] = hF16;
            hnB[quad * HPAD + j] = hB16;
            hbF[(size_t)tF * 512 + hoff] = hF16;
            hbB[(size_t)tB * 512 + hoff] = hB16;

            lds_barrier();   // new h visible; old buffers free
        }
    }
}

// -------- K4: Y = tanh(Hout @ W_h2o^T + b), score = sum(Y*u_w), 4 t per block
__global__ __launch_bounds__(256) void k4_scores(const bf16_t* __restrict__ hist2,
                                                 const bf16_t* __restrict__ wh2o_bf,
                                                 const float* __restrict__ bh2o,
                                                 const float* __restrict__ uw,
                                                 float* __restrict__ scores) {
    int blk = blockIdx.x;           // 0..511 = tq*4 + g
    int tq = blk >> 2;
    int g = blk & 3;                // 16-sample tile = groups 4g..4g+3
    int lane = threadIdx.x & 63;
    int w2 = threadIdx.x >> 6;
    int quad = lane >> 4, col = lane & 15;

    float p4[4][4];
#pragma unroll
    for (int tt = 0; tt < 4; ++tt)
#pragma unroll
        for (int r = 0; r < 4; ++r) p4[tt][r] = 0.f;

#pragma unroll
    for (int tt = 0; tt < 4; ++tt) {
        int t = 4 * tq + tt;
        // A fragments: sample (4g + col>>2, col&3) at t; K=256: h_f then h_b
        bf16x8 a[8];
#pragma unroll
        for (int kc = 0; kc < 8; ++kc) {
            int dir = kc >> 2;
            a[kc] = ldb8(hist2 + ((size_t)(dir * 16 + 4 * g + (col >> 2)) * TT + t) * 512
                         + (col & 3) * 128 + (kc & 3) * 32 + quad * 8);
        }
#pragma unroll
        for (int tl = 0; tl < 2; ++tl) {
            int n = 32 * w2 + 16 * tl + col;
            floatx4 acc = {0.f, 0.f, 0.f, 0.f};
#pragma unroll
            for (int kc = 0; kc < 8; ++kc) {
                bf16x8 bw = ldb8(wh2o_bf + (size_t)n * 256 + kc * 32 + quad * 8);
                acc = __builtin_amdgcn_mfma_f32_16x16x32_bf16(a[kc], bw, acc, 0, 0, 0);
            }
            float bias = bh2o[n];
            float u = uw[n];
#pragma unroll
            for (int r = 0; r < 4; ++r) {
                float y = tanh_f(acc[r] + bias);
                p4[tt][r] += y * u;
            }
        }
    }
    // reduce over the 16 cols of this quad group (rows identical across them)
#pragma unroll
    for (int m = 1; m < 16; m <<= 1)
#pragma unroll
        for (int tt = 0; tt < 4; ++tt)
#pragma unroll
            for (int r = 0; r < 4; ++r)
                p4[tt][r] += __shfl_xor(p4[tt][r], m, 64);

    __shared__ float part[4][16][4];
    if (col == 0) {
#pragma unroll
        for (int tt = 0; tt < 4; ++tt)
#pragma unroll
            for (int r = 0; r < 4; ++r) part[tt][quad * 4 + r][w2] = p4[tt][r];
    }
    __syncthreads();
    if (threadIdx.x < 64) {
        int tt = threadIdx.x >> 4;
        int row = threadIdx.x & 15;
        float s = part[tt][row][0] + part[tt][row][1] +
                  part[tt][row][2] + part[tt][row][3];
        scores[(size_t)(g * 16 + row) * TT + 4 * tq + tt] = s;
    }
}

// -------- K5: per-sample softmax over valid t + pooled = sum_t alpha[t]*Hout[b][t][:]
__global__ __launch_bounds__(512) void k5_pool(const float* __restrict__ scores,
                                               const bf16_t* __restrict__ hist2,
                                               const int* __restrict__ lens,
                                               float* __restrict__ out) {
    int b = blockIdx.x;
    int g16 = b >> 2, bl = b & 3;
    int tid = threadIdx.x;
    int len = lens[b];
    __shared__ float alpha[TT];
    __shared__ float red[512];
    const float* srow = scores + (size_t)b * TT;

    float m = -1e30f;
    for (int t = tid; t < len; t += 512) m = fmaxf(m, srow[t]);
    red[tid] = m;
    __syncthreads();
    for (int s = 256; s > 0; s >>= 1) {
        if (tid < s) red[tid] = fmaxf(red[tid], red[tid + s]);
        __syncthreads();
    }
    float mx = red[0];
    __syncthreads();

    float sum = 0.f;
    for (int t = tid; t < TT; t += 512) {
        float e = (t < len) ? __expf(srow[t] - mx) : 0.f;
        alpha[t] = e;
        sum += e;
    }
    red[tid] = sum;
    __syncthreads();
    for (int s = 256; s > 0; s >>= 1) {
        if (tid < s) red[tid] += red[tid + s];
        __syncthreads();
    }
    float inv = fast_rcp(red[0]);
    __syncthreads();

    // 512 threads = 2 t-halves x 256 channels
    int c = tid & 255;           // output channel
    int half = tid >> 8;
    int dir = c >> 7;
    int j = c & 127;
    const bf16_t* hbase = hist2 + (size_t)(dir * 16 + g16) * TT * 512 + bl * 128 + j;
    float acc = 0.f;
    for (int t = half; t < len; t += 2)
        acc += alpha[t] * (float)hbase[(size_t)t * 512];
    red[tid] = acc;
    __syncthreads();
    if (tid < 256)
        out[(size_t)b * 256 + tid] = (red[tid] + red[tid + 256]) * inv;
}

extern "C" void kernel_launch(void* const* d_in, const int* in_sizes, int n_in,
                              void* d_out, int out_size, void* d_ws, size_t ws_size,
                              hipStream_t stream) {
    const int* X       = (const int*)d_in[0];
    const int* lens    = (const int*)d_in[1];
    const float* emb   = (const float*)d_in[3];
    const float* We2i  = (const float*)d_in[4];
    const float* be2i  = (const float*)d_in[5];
    const float* Wihf  = (const float*)d_in[6];
    const float* Whhf  = (const float*)d_in[7];
    const float* bihf  = (const float*)d_in[8];
    const float* bhhf  = (const float*)d_in[9];
    const float* Wihb  = (const float*)d_in[10];
    const float* Whhb  = (const float*)d_in[11];
    const float* bihb  = (const float*)d_in[12];
    const float* bhhb  = (const float*)d_in[13];
    const float* Wh2o  = (const float*)d_in[14];
    const float* bh2o  = (const float*)d_in[15];
    const float* uw    = (const float*)d_in[16];

    char* ws = (char*)d_ws;
    size_t off = 0;
    bf16_t* we_bf = (bf16_t*)(ws + off);   off += (size_t)HH * EE * 2;          // 32 KB
    bf16_t* wih_bf = (bf16_t*)(ws + off);  off += (size_t)2 * 384 * HH * 2;     // 192 KB
    bf16_t* whh_bf = (bf16_t*)(ws + off);  off += (size_t)2 * 384 * HH * 2;     // 192 KB
    bf16_t* wh2o_bf = (bf16_t*)(ws + off); off += (size_t)OO * 256 * 2;         // 64 KB
    float* gxbias = (float*)(ws + off);    off += 768 * 4;                      // 3 KB
    off = (off + 255) & ~(size_t)255;
    bf16_t* gx3 = (bf16_t*)(ws + off);     off += (size_t)32 * TT * 384 * 4 * 2; // 50.3 MB
    bf16_t* hist2 = (bf16_t*)(ws + off);   off += (size_t)32 * TT * 4 * 128 * 2; // 16.8 MB
    float* scores = (float*)(ws + off);    off += (size_t)BB * TT * 4;           // 0.13 MB

    float* out = (float*)d_out;

    k0_conv<<<dim3(256), dim3(256), 0, stream>>>(We2i, Wihf, Wihb, Whhf, Whhb,
                                                 Wh2o, bihf, bhhf, bihb, bhhb,
                                                 we_bf, wih_bf, whh_bf, wh2o_bf, gxbias);
    k12_gx<<<dim3(TT), dim3(256), 0, stream>>>(X, emb, we_bf, be2i, wih_bf, gxbias, gx3);
    k3_gru<<<dim3(16), dim3(512), 0, stream>>>(gx3, whh_bf, bhhf, bhhb, lens, hist2);
    k4_scores<<<dim3(TT), dim3(256), 0, stream>>>(hist2, wh2o_bf, bh2o, uw, scores);
    k5_pool<<<dim3(BB), dim3(512), 0, stream>>>(scores, hist2, lens, out);
}

// Round 11
// 394.937 us; speedup vs baseline: 1.4581x; 1.4581x over previous
//
#include <hip/hip_runtime.h>
#include <hip/hip_bf16.h>

// Shapes (fixed by the problem)
#define VV 50000
#define EE 128
#define HH 128
#define OO 128
#define BB 64
#define TT 512

typedef __bf16 bf16_t;
typedef __attribute__((ext_vector_type(8))) __bf16 bf16x8;
typedef __attribute__((ext_vector_type(4))) __bf16 bf16x4;
typedef __attribute__((ext_vector_type(4))) float floatx4;

__device__ __forceinline__ bf16x8 ldb8(const bf16_t* p) {
    return *reinterpret_cast<const bf16x8*>(p);
}

// load 8 consecutive fp32, round to bf16 fragment (two float4 loads)
__device__ __forceinline__ bf16x8 ldf8_bf(const float* p) {
    const float4* q = reinterpret_cast<const float4*>(p);
    float4 u = q[0], v = q[1];
    bf16x8 r;
    r[0] = (__bf16)u.x; r[1] = (__bf16)u.y; r[2] = (__bf16)u.z; r[3] = (__bf16)u.w;
    r[4] = (__bf16)v.x; r[5] = (__bf16)v.y; r[6] = (__bf16)v.z; r[7] = (__bf16)v.w;
    return r;
}

__device__ __forceinline__ float fast_rcp(float x) { return __builtin_amdgcn_rcpf(x); }
__device__ __forceinline__ float sigmoid_f(float x) {
    return fast_rcp(1.0f + __expf(-x));
}
__device__ __forceinline__ float tanh_f(float x) {
    float e = __expf(2.0f * x);
    return 1.0f - 2.0f * fast_rcp(e + 1.0f);
}

// LDS-only barrier: wait LDS ops, sync — do NOT drain vmcnt (hist stores and
// gx ring-prefetch loads stay in flight across steps).
__device__ __forceinline__ void lds_barrier() {
    asm volatile("s_waitcnt lgkmcnt(0)\n\ts_barrier" ::: "memory");
}

// -------- K0: preconvert small weights fp32->bf16 + fold gx bias.
__global__ __launch_bounds__(256) void k0_conv(
    const float* __restrict__ we,
    const float* __restrict__ wihf, const float* __restrict__ wihb,
    const float* __restrict__ whhf, const float* __restrict__ whhb,
    const float* __restrict__ wh2o,
    const float* __restrict__ bihf, const float* __restrict__ bhhf,
    const float* __restrict__ bihb, const float* __restrict__ bhhb,
    bf16_t* __restrict__ we_bf,
    bf16_t* __restrict__ wih_bf, bf16_t* __restrict__ whh_bf,
    bf16_t* __restrict__ wh2o_bf, float* __restrict__ gxbias) {
    int tid = blockIdx.x * 256 + threadIdx.x;
    int np = gridDim.x * 256;
    for (int i = tid; i < HH * EE; i += np) we_bf[i] = (bf16_t)we[i];
    for (int i = tid; i < 384 * HH; i += np) {
        wih_bf[i] = (bf16_t)wihf[i];
        wih_bf[384 * HH + i] = (bf16_t)wihb[i];
        whh_bf[i] = (bf16_t)whhf[i];
        whh_bf[384 * HH + i] = (bf16_t)whhb[i];
    }
    for (int i = tid; i < OO * 256; i += np) wh2o_bf[i] = (bf16_t)wh2o[i];
    if (tid < 768) {
        int dir = tid / 384, n = tid % 384;
        const float* bih = dir ? bihb : bihf;
        const float* bhh = dir ? bhhb : bhhf;
        gxbias[tid] = bih[n] + (n < 256 ? bhh[n] : 0.0f);  // bhh_n goes in K3's C-init
    }
}

// -------- K12 (fused K1+K2), 4 timesteps per block, with dead-time skip:
// lens sorted descending -> tile g's max len = lens[16g]; blocks entirely past
// it produce gx no one reads (K3 stops at its group Lmax <= lens[16g]).
__global__ __launch_bounds__(256) void k12_gx(const int* __restrict__ X,
                                              const float* __restrict__ emb,
                                              const bf16_t* __restrict__ we_bf,
                                              const float* __restrict__ be,
                                              const bf16_t* __restrict__ wih_bf,
                                              const float* __restrict__ gxbias,
                                              const int* __restrict__ lens,
                                              bf16_t* __restrict__ gx3) {
    int blk = blockIdx.x;            // 0..511 = tq*4 + g
    int tq = blk >> 2;
    int g = blk & 3;                 // 16-sample tile
    if (4 * tq >= lens[16 * g]) return;   // uniform: whole block dead

    int lane = threadIdx.x & 63;
    int w2 = threadIdx.x >> 6;       // wave 0..3
    int quad = lane >> 4, col = lane & 15;

    __shared__ bf16_t xs[4][16 * 136];   // 4 xh tiles, row-padded

    // stage 1 x4: xh = emb[X] @ We^T + be (A rows = 16 samples at t=4tq+tt)
#pragma unroll
    for (int tt = 0; tt < 4; ++tt) {
        int t = 4 * tq + tt;
        int v = X[(g * 16 + col) * TT + t];
        bf16x8 a[4];
#pragma unroll
        for (int kc = 0; kc < 4; ++kc)
            a[kc] = ldf8_bf(emb + (size_t)v * EE + kc * 32 + quad * 8);
#pragma unroll
        for (int tl = 0; tl < 2; ++tl) {
            int n = 32 * w2 + 16 * tl + col;
            floatx4 acc = {0.f, 0.f, 0.f, 0.f};
#pragma unroll
            for (int kc = 0; kc < 4; ++kc) {
                bf16x8 bw = ldb8(we_bf + (size_t)n * EE + kc * 32 + quad * 8);
                acc = __builtin_amdgcn_mfma_f32_16x16x32_bf16(a[kc], bw, acc, 0, 0, 0);
            }
            float bias = be[n];
#pragma unroll
            for (int r = 0; r < 4; ++r)
                xs[tt][(quad * 4 + r) * 136 + n] = (bf16_t)(acc[r] + bias);
        }
    }
    __syncthreads();

    // stage 2: gx = xh @ Wih^T + gxbias, both dirs; Wih loaded once per n-tile
    bf16x8 a2[4][4];
#pragma unroll
    for (int tt = 0; tt < 4; ++tt)
#pragma unroll
        for (int kc = 0; kc < 4; ++kc)
            a2[tt][kc] = ldb8(xs[tt] + col * 136 + kc * 32 + quad * 8);

#pragma unroll
    for (int tl = 0; tl < 12; ++tl) {
        int idx = w2 * 12 + tl;          // 0..47
        int dir = idx >= 24;
        int n = (idx - dir * 24) * 16 + col;   // 0..383
        bf16x8 bw[4];
#pragma unroll
        for (int kc = 0; kc < 4; ++kc)
            bw[kc] = ldb8(wih_bf + ((size_t)dir * 384 + n) * HH + kc * 32 + quad * 8);
        float bias = gxbias[dir * 384 + n];
#pragma unroll
        for (int tt = 0; tt < 4; ++tt) {
            int t = 4 * tq + tt;
            floatx4 acc = {0.f, 0.f, 0.f, 0.f};
#pragma unroll
            for (int kc = 0; kc < 4; ++kc)
                acc = __builtin_amdgcn_mfma_f32_16x16x32_bf16(a2[tt][kc], bw[kc], acc, 0, 0, 0);
            bf16x4 pack;
#pragma unroll
            for (int r = 0; r < 4; ++r)
                pack[r] = (__bf16)(acc[r] + bias);   // D row r -> sample 16g+quad*4+r
            *reinterpret_cast<bf16x4*>(
                gx3 + (((size_t)(dir * 16 + 4 * g + quad) * TT + t) * 384 + n) * 4) = pack;
        }
    }
}

// -------- K3: masked GRU recurrence (R9 version — measured 204 us).
// grid (16 groups of 4 samples, 2 dirs) = 32 blocks, 512 threads = 8 waves.
// Broadcast A-layout: A row m = h[sample m&3] -> D rows repeat with period 4,
// so the gates for this lane's sample (=quad) are already local (cndmask tree).
#define HPAD 144
#define HBUF (4 * HPAD)
__global__ __launch_bounds__(512) void k3_gru(const bf16_t* __restrict__ gx3,
                                              const bf16_t* __restrict__ whh_bf,
                                              const float* __restrict__ bhh_f,
                                              const float* __restrict__ bhh_b,
                                              const int* __restrict__ lens,
                                              bf16_t* __restrict__ hist2) {
    int g16 = blockIdx.x;    // 4-sample group: samples 4*g16 .. 4*g16+3
    int dir = blockIdx.y;
    const float* bhh = dir ? bhh_b : bhh_f;

    int tid = threadIdx.x;
    int w = tid >> 6;        // wave 0..7
    int lane = tid & 63;
    int quad = lane >> 4, col = lane & 15;
    int j = 16 * w + col;    // owned hidden column

    __shared__ bf16_t hl[2 * HBUF];   // double-buffered h, 4 rows (samples)
    for (int i = tid; i < 2 * HBUF; i += 512) hl[i] = (bf16_t)0.f;

    int len1 = lens[4 * g16 + quad];      // this lane's sample
    int Lmax = max(max(lens[4 * g16], lens[4 * g16 + 1]),
                   max(lens[4 * g16 + 2], lens[4 * g16 + 3]));

    float bhn = bhh[256 + j];

    // Whh B-fragments (pre-converted bf16), resident for all steps
    bf16x8 Bw[3][4];
#pragma unroll
    for (int gate = 0; gate < 3; ++gate)
#pragma unroll
        for (int kc = 0; kc < 4; ++kc)
            Bw[gate][kc] = ldb8(whh_bf + ((size_t)dir * 384 + gate * 128 + j) * HH + kc * 32 + quad * 8);

    const bf16_t* gbase = gx3 + (size_t)(dir * 16 + g16) * TT * 1536;
    bf16_t* hb = hist2 + (size_t)(dir * 16 + g16) * TT * 512;
    int loff[3];
#pragma unroll
    for (int gate = 0; gate < 3; ++gate)
        loff[gate] = (gate * 128 + j) * 4 + quad;
    int hoff = quad * 128 + j;
    int aoff = (col & 3) * HPAD + quad * 8;   // broadcast A-read offset

    float h = 0.f;
    int S4 = (Lmax + 3) & ~3;
    bool lowquad = (quad & 1) == 0;
    bool lowhalf = (quad & 2) == 0;

    // prefetch ring, depth 4 (raw bf16 scalars; convert at consumption)
    __bf16 ring[4][3];
#pragma unroll
    for (int u = 0; u < 4; ++u) {
        int tr = dir ? (Lmax - 1 - u) : u;
        int t = min(max(tr, 0), Lmax - 1);
#pragma unroll
        for (int gate = 0; gate < 3; ++gate)
            ring[u][gate] = gbase[(size_t)t * 1536 + loff[gate]];
    }
    lds_barrier();   // zero-init visible

    for (int sb = 0; sb < S4; sb += 4) {
#pragma unroll
        for (int u = 0; u < 4; ++u) {
            int s = sb + u;
            int tr = dir ? (Lmax - 1 - s) : s;
            int t = min(max(tr, 0), Lmax - 1);     // clamped for tail steps
            const bf16_t* hc = hl + (s & 1) * HBUF;
            bf16_t* hn = hl + ((s + 1) & 1) * HBUF;

            // consume ring slot u (loads issued 4 steps ago)
            float gx0 = (float)ring[u][0];
            float gx1 = (float)ring[u][1];
            float gx2 = (float)ring[u][2];

            // A fragments from LDS h (broadcast rows: sample = row & 3)
            bf16x8 a[4];
#pragma unroll
            for (int kc = 0; kc < 4; ++kc)
                a[kc] = ldb8(hc + aoff + kc * 32);

            // 3 chains; bhn folded into n-gate C-init
            floatx4 cr = {0.f, 0.f, 0.f, 0.f};
            floatx4 cz = {0.f, 0.f, 0.f, 0.f};
            floatx4 cn = {bhn, bhn, bhn, bhn};
#pragma unroll
            for (int kc = 0; kc < 4; ++kc) {
                cr = __builtin_amdgcn_mfma_f32_16x16x32_bf16(a[kc], Bw[0][kc], cr, 0, 0, 0);
                cz = __builtin_amdgcn_mfma_f32_16x16x32_bf16(a[kc], Bw[1][kc], cz, 0, 0, 0);
                cn = __builtin_amdgcn_mfma_f32_16x16x32_bf16(a[kc], Bw[2][kc], cn, 0, 0, 0);
            }

            // refill ring slot u for step s+4
            {
                int sn = s + 4;
                int trn = dir ? (Lmax - 1 - sn) : sn;
                int tn = min(max(trn, 0), Lmax - 1);
#pragma unroll
                for (int gate = 0; gate < 3; ++gate)
                    ring[u][gate] = gbase[(size_t)tn * 1536 + loff[gate]];
            }

            // register select: reg r = gates of sample r (D-row periodicity);
            // this lane's sample is quad -> pick reg[quad]. No cross-lane ops.
            float aR = lowhalf ? (lowquad ? cr[0] : cr[1]) : (lowquad ? cr[2] : cr[3]);
            float aZ = lowhalf ? (lowquad ? cz[0] : cz[1]) : (lowquad ? cz[2] : cz[3]);
            float aN = lowhalf ? (lowquad ? cn[0] : cn[1]) : (lowquad ? cn[2] : cn[3]);

            // gate math: ONE channel (sample=quad, hidden=j) per lane
            float rg = sigmoid_f(aR + gx0);
            float zg = sigmoid_f(aZ + gx1);
            float ng = tanh_f(gx2 + rg * aN);
            float hnew = ng + zg * (h - ng);
            bool upd = (s < Lmax) && (t < len1);
            h = upd ? hnew : h;
            bf16_t h16 = (bf16_t)h;
            hn[quad * HPAD + j] = h16;            // LDS row = sample
            hb[(size_t)t * 512 + hoff] = h16;     // hist2 per-block region

            lds_barrier();   // new h visible; old buffer free
        }
    }
}

// -------- K45 (fused K4+K5): one block per sample. Per 16-t chunk (only
// t < len): scores via MFMA with M-dim = time (A rows = 16 consecutive t,
// K=256 over h_f||h_b, N=128 output channels), then in-block softmax over
// valid t and pooled = sum_t alpha[t]*Hout[b][t][:]. hist2 rows at t>=len are
// stale/poison but FINITE (0xAA bf16 = -3e-13) and masked by t<len.
__global__ __launch_bounds__(256) void k45_pool(const bf16_t* __restrict__ hist2,
                                                const bf16_t* __restrict__ wh2o_bf,
                                                const float* __restrict__ bh2o,
                                                const float* __restrict__ uw,
                                                const int* __restrict__ lens,
                                                float* __restrict__ out) {
    int b = blockIdx.x;
    int g16 = b >> 2, bl = b & 3;
    int tid = threadIdx.x;
    int lane = tid & 63, w2 = tid >> 6;       // 4 waves
    int quad = lane >> 4, col = lane & 15;
    int len = lens[b];

    __shared__ float smax[TT][4];   // per-wave partial scores, 8 KB
    __shared__ float alpha[TT];
    __shared__ float red[256];

    const bf16_t* hf = hist2 + (size_t)g16 * TT * 512 + bl * 128;        // fwd
    const bf16_t* hbk = hist2 + (size_t)(16 + g16) * TT * 512 + bl * 128; // bwd

    // this wave's 2 n-tiles (N=128 total over 4 waves)
    int n0 = (w2 * 2 + 0) * 16 + col;
    int n1 = (w2 * 2 + 1) * 16 + col;
    float bias0 = bh2o[n0], u0 = uw[n0];
    float bias1 = bh2o[n1], u1 = uw[n1];

    int nch = (len + 15) >> 4;
    for (int ch = 0; ch < nch; ++ch) {
        int t0 = ch * 16;
        int t = t0 + col;                 // A row m = t offset (t <= 511)
        bf16x8 a[8];
#pragma unroll
        for (int kc = 0; kc < 4; ++kc) {
            a[kc]     = ldb8(hf  + (size_t)t * 512 + kc * 32 + quad * 8);
            a[kc + 4] = ldb8(hbk + (size_t)t * 512 + kc * 32 + quad * 8);
        }
        float p4[4] = {0.f, 0.f, 0.f, 0.f};
#pragma unroll
        for (int tl = 0; tl < 2; ++tl) {
            int n = tl ? n1 : n0;
            float bias = tl ? bias1 : bias0;
            float u = tl ? u1 : u0;
            floatx4 acc = {0.f, 0.f, 0.f, 0.f};
#pragma unroll
            for (int kc = 0; kc < 8; ++kc) {
                bf16x8 bw = ldb8(wh2o_bf + (size_t)n * 256 + kc * 32 + quad * 8);
                acc = __builtin_amdgcn_mfma_f32_16x16x32_bf16(a[kc], bw, acc, 0, 0, 0);
            }
#pragma unroll
            for (int r = 0; r < 4; ++r)
                p4[r] += tanh_f(acc[r] + bias) * u;
        }
        // reduce over the 16 cols of this quad group (D rows = t's)
#pragma unroll
        for (int m = 1; m < 16; m <<= 1)
#pragma unroll
            for (int r = 0; r < 4; ++r)
                p4[r] += __shfl_xor(p4[r], m, 64);
        if (col == 0) {
#pragma unroll
            for (int r = 0; r < 4; ++r)
                smax[t0 + quad * 4 + r][w2] = p4[r];
        }
    }
    __syncthreads();

    // softmax over valid t
    float mx = -1e30f;
    for (int t = tid; t < TT; t += 256) {
        float s = -1e30f;
        if (t < len) s = smax[t][0] + smax[t][1] + smax[t][2] + smax[t][3];
        alpha[t] = s;
        mx = fmaxf(mx, s);
    }
    red[tid] = mx;
    __syncthreads();
    for (int s = 128; s > 0; s >>= 1) {
        if (tid < s) red[tid] = fmaxf(red[tid], red[tid + s]);
        __syncthreads();
    }
    mx = red[0];
    __syncthreads();
    float sum = 0.f;
    for (int t = tid; t < TT; t += 256) {
        float e = (t < len) ? __expf(alpha[t] - mx) : 0.f;
        alpha[t] = e;
        sum += e;
    }
    red[tid] = sum;
    __syncthreads();
    for (int s = 128; s > 0; s >>= 1) {
        if (tid < s) red[tid] += red[tid + s];
        __syncthreads();
    }
    float inv = fast_rcp(red[0]);
    __syncthreads();

    // pooled: 256 threads = 256 output channels
    int c = tid;
    int dir = c >> 7;
    int j = c & 127;
    const bf16_t* hbase = (dir ? hbk : hf) + j;
    float acc = 0.f;
    int t = 0;
    for (; t + 4 <= len; t += 4) {
        acc += alpha[t + 0] * (float)hbase[(size_t)(t + 0) * 512];
        acc += alpha[t + 1] * (float)hbase[(size_t)(t + 1) * 512];
        acc += alpha[t + 2] * (float)hbase[(size_t)(t + 2) * 512];
        acc += alpha[t + 3] * (float)hbase[(size_t)(t + 3) * 512];
    }
    for (; t < len; ++t) acc += alpha[t] * (float)hbase[(size_t)t * 512];

    out[(size_t)b * 256 + c] = acc * inv;
}

extern "C" void kernel_launch(void* const* d_in, const int* in_sizes, int n_in,
                              void* d_out, int out_size, void* d_ws, size_t ws_size,
                              hipStream_t stream) {
    const int* X       = (const int*)d_in[0];
    const int* lens    = (const int*)d_in[1];
    const float* emb   = (const float*)d_in[3];
    const float* We2i  = (const float*)d_in[4];
    const float* be2i  = (const float*)d_in[5];
    const float* Wihf  = (const float*)d_in[6];
    const float* Whhf  = (const float*)d_in[7];
    const float* bihf  = (const float*)d_in[8];
    const float* bhhf  = (const float*)d_in[9];
    const float* Wihb  = (const float*)d_in[10];
    const float* Whhb  = (const float*)d_in[11];
    const float* bihb  = (const float*)d_in[12];
    const float* bhhb  = (const float*)d_in[13];
    const float* Wh2o  = (const float*)d_in[14];
    const float* bh2o  = (const float*)d_in[15];
    const float* uw    = (const float*)d_in[16];

    char* ws = (char*)d_ws;
    size_t off = 0;
    bf16_t* we_bf = (bf16_t*)(ws + off);   off += (size_t)HH * EE * 2;          // 32 KB
    bf16_t* wih_bf = (bf16_t*)(ws + off);  off += (size_t)2 * 384 * HH * 2;     // 192 KB
    bf16_t* whh_bf = (bf16_t*)(ws + off);  off += (size_t)2 * 384 * HH * 2;     // 192 KB
    bf16_t* wh2o_bf = (bf16_t*)(ws + off); off += (size_t)OO * 256 * 2;         // 64 KB
    float* gxbias = (float*)(ws + off);    off += 768 * 4;                      // 3 KB
    off = (off + 255) & ~(size_t)255;
    bf16_t* gx3 = (bf16_t*)(ws + off);     off += (size_t)32 * TT * 384 * 4 * 2; // 50.3 MB
    bf16_t* hist2 = (bf16_t*)(ws + off);   off += (size_t)32 * TT * 4 * 128 * 2; // 16.8 MB

    float* out = (float*)d_out;

    k0_conv<<<dim3(256), dim3(256), 0, stream>>>(We2i, Wihf, Wihb, Whhf, Whhb,
                                                 Wh2o, bihf, bhhf, bihb, bhhb,
                                                 we_bf, wih_bf, whh_bf, wh2o_bf, gxbias);
    k12_gx<<<dim3(TT), dim3(256), 0, stream>>>(X, emb, we_bf, be2i, wih_bf, gxbias, lens, gx3);
    k3_gru<<<dim3(16, 2), dim3(512), 0, stream>>>(gx3, whh_bf, bhhf, bhhb, lens, hist2);
    k45_pool<<<dim3(BB), dim3(256), 0, stream>>>(hist2, wh2o_bf, bh2o, uw, lens, out);
}